// Round 1
// baseline (39.144 us; speedup 1.0000x reference)
//
#include <hip/hip_runtime.h>
#include <math.h>

#define Bq 4
#define Kq 16
#define Nq 2048
#define Dq 256
#define XPAD 260   // padded LDS row stride (floats): multiple of 4 for float4, breaks 32-bank aliasing

// ws layout (floats):
//   [0      .. 1024)  : S1[b][16][16]  = M1[b]^2
//   [1024   .. 2048)  : G_I[b][16][16] = I[b] I[b]^T
//   [2048   .. 10240) : logits (B=4, N=2048) row-major

// All 256 threads participate; thread tid owns entry (i,j) = (tid>>4, tid&15).
// Computes g = X[i].X[j]  (Gram entry), then Gauss-Jordan solves
//   (G + lam I) M = (rho-1) G - lam I   ->  M = rho*G(G+lam I)^{-1} - I  (symmetric)
// and returns s = (M*M)[i][j].
__device__ __forceinline__ void gram_solve_S(float (*X)[XPAD], float (*Aug)[2 * Kq],
                                             float lam, float rho, int i, int j,
                                             float* g_out, float* s_out) {
    float g = 0.f;
#pragma unroll 4
    for (int dd = 0; dd < Dq; dd += 4) {
        const float4 a = *reinterpret_cast<const float4*>(&X[i][dd]);
        const float4 b = *reinterpret_cast<const float4*>(&X[j][dd]);
        g += a.x * b.x + a.y * b.y + a.z * b.z + a.w * b.w;
    }
    Aug[i][j]      = g + (i == j ? lam : 0.f);
    Aug[i][j + Kq] = (rho - 1.f) * g - (i == j ? lam : 0.f);
    __syncthreads();

    // Gauss-Jordan, no pivoting (A is SPD, cond ~ 3).
    for (int k = 0; k < Kq; ++k) {
        const float piv  = Aug[k][k];
        const float pinv = 1.f / piv;
        const float fac  = Aug[i][k] * pinv;
        const float pkc  = Aug[k][j];
        const float pkc2 = Aug[k][j + Kq];
        __syncthreads();
        if (i == k) {
            Aug[i][j]      = pkc * pinv;
            Aug[i][j + Kq] = pkc2 * pinv;
        } else {
            Aug[i][j]      -= fac * pkc;
            Aug[i][j + Kq] -= fac * pkc2;
        }
        __syncthreads();
    }

    // S = M * M  (M symmetric, stored in Aug[:, 16:32])
    float s = 0.f;
#pragma unroll
    for (int k = 0; k < Kq; ++k) s += Aug[i][k + Kq] * Aug[k][j + Kq];
    *g_out = g;
    *s_out = s;
}

__global__ __launch_bounds__(256) void phase1_kernel(const float* __restrict__ img,
                                                     const float* __restrict__ r,
                                                     float* __restrict__ ws) {
    __shared__ __align__(16) float X[Kq][XPAD];
    __shared__ float Aug[Kq][2 * Kq];
    const int b   = blockIdx.x;
    const int tid = threadIdx.x;
    const float* Ib = img + b * (Kq * Dq);
    for (int idx = tid; idx < Kq * Dq; idx += 256)
        X[idx >> 8][idx & 255] = Ib[idx];
    __syncthreads();

    const int i = tid >> 4, j = tid & 15;
    const float lam = (float(Bq) / float(Dq)) * expf(r[0]) + 1e-6f;
    const float rho = expf(r[1]);
    float g, s;
    gram_solve_S(X, Aug, lam, rho, i, j, &g, &s);
    ws[b * 256 + tid]        = s;  // S1[b]
    ws[1024 + b * 256 + tid] = g;  // G_I[b]
}

__global__ __launch_bounds__(256) void phase2_kernel(const float* __restrict__ text,
                                                     const float* __restrict__ r,
                                                     const float* __restrict__ alp,
                                                     const float* __restrict__ scale,
                                                     const float* __restrict__ sg,
                                                     float* __restrict__ logits) {
    __shared__ __align__(16) float X[Kq][XPAD];
    __shared__ float Aug[Kq][2 * Kq];
    __shared__ float rr[4][8];
    const int n   = blockIdx.x;
    const int tid = threadIdx.x;
    const float* Tn = text + n * (Kq * Dq);
    for (int idx = tid; idx < Kq * Dq; idx += 256)
        X[idx >> 8][idx & 255] = Tn[idx];
    __syncthreads();

    const int i = tid >> 4, j = tid & 15;
    const float lam = (float(Nq) / float(Dq)) * expf(r[2]) + 1e-6f;
    const float rho = expf(r[3]);
    float g, s;
    gram_solve_S(X, Aug, lam, rho, i, j, &g, &s);

    // p[b]   = <S1[b], G_T> partial ; p[4+b] = <S2, G_I[b]> partial
    float p[8];
#pragma unroll
    for (int b = 0; b < 4; ++b) {
        p[b]     = g * sg[b * 256 + tid];
        p[4 + b] = s * sg[1024 + b * 256 + tid];
    }
#pragma unroll
    for (int off = 32; off; off >>= 1) {
#pragma unroll
        for (int q = 0; q < 8; ++q) p[q] += __shfl_down(p[q], off, 64);
    }
    const int wave = tid >> 6, lane = tid & 63;
    if (lane == 0) {
#pragma unroll
        for (int q = 0; q < 8; ++q) rr[wave][q] = p[q];
    }
    __syncthreads();
    if (tid < 4) {
        const int b = tid;
        const float d1 = -(rr[0][b] + rr[1][b] + rr[2][b] + rr[3][b]) * (1.f / Kq);
        const float d2 = -(rr[0][b + 4] + rr[1][b + 4] + rr[2][b + 4] + rr[3][b + 4]) * (1.f / Kq);
        const float a  = alp[0];
        logits[b * Nq + n] = scale[0] * (a * d1 + (1.f - a) * d2);
    }
}

__global__ __launch_bounds__(256) void phase3_kernel(const float* __restrict__ logits,
                                                     const float* __restrict__ lsc,
                                                     float* __restrict__ out) {
    const int b   = blockIdx.x;
    const int tid = threadIdx.x;
    const float* row = logits + b * Nq;
    __shared__ float sh[4];
    float v[8];
    float mx = -INFINITY;
#pragma unroll
    for (int q = 0; q < 8; ++q) {
        v[q] = row[tid + q * 256];
        mx = fmaxf(mx, v[q]);
    }
#pragma unroll
    for (int off = 32; off; off >>= 1) mx = fmaxf(mx, __shfl_down(mx, off, 64));
    if ((tid & 63) == 0) sh[tid >> 6] = mx;
    __syncthreads();
    mx = fmaxf(fmaxf(sh[0], sh[1]), fmaxf(sh[2], sh[3]));

    float sum = 0.f;
#pragma unroll
    for (int q = 0; q < 8; ++q) sum += expf(v[q] - mx);
#pragma unroll
    for (int off = 32; off; off >>= 1) sum += __shfl_down(sum, off, 64);
    __syncthreads();  // protect sh before reuse
    if ((tid & 63) == 0) sh[tid >> 6] = sum;
    __syncthreads();
    sum = sh[0] + sh[1] + sh[2] + sh[3];

    const float lse = mx + logf(sum);
#pragma unroll
    for (int q = 0; q < 8; ++q) out[b * Nq + tid + q * 256] = v[q] - lse;
    if (b == 0 && tid == 0) out[Bq * Nq] = 1.f / (1.f + expf(-lsc[0]));
}

extern "C" void kernel_launch(void* const* d_in, const int* in_sizes, int n_in,
                              void* d_out, int out_size, void* d_ws, size_t ws_size,
                              hipStream_t stream) {
    const float* img   = (const float*)d_in[0];
    const float* text  = (const float*)d_in[1];
    const float* r     = (const float*)d_in[2];
    const float* alp   = (const float*)d_in[3];
    const float* scale = (const float*)d_in[4];
    const float* lsc   = (const float*)d_in[5];
    float* ws  = (float*)d_ws;
    float* out = (float*)d_out;

    phase1_kernel<<<Bq, 256, 0, stream>>>(img, r, ws);
    phase2_kernel<<<Nq, 256, 0, stream>>>(text, r, alp, scale, ws, ws + 2048);
    phase3_kernel<<<Bq, 256, 0, stream>>>(ws + 2048, lsc, out);
}

// Round 2
// 25.030 us; speedup vs baseline: 1.5639x; 1.5639x over previous
//
#include <hip/hip_runtime.h>
#include <math.h>

#define Bq 4
#define Kq 16
#define Nq 2048
#define Dq 256

typedef float f32x4 __attribute__((ext_vector_type(4)));
typedef short s16x8 __attribute__((ext_vector_type(8)));

// ws layout (floats):
//   [0    .. 1024)  : S1  in lane layout: [b][lane][q] (float4 per lane)
//   [1024 .. 2048)  : G_I in lane layout: [b][lane][q]
//   [2048 .. 10240) : logits (B=4, N=2048) row-major

static __device__ __forceinline__ unsigned short f2bf(float x) {
    union { float f; unsigned u; } v; v.f = x;
    unsigned r = v.u + 0x7fff + ((v.u >> 16) & 1);  // RNE
    return (unsigned short)(r >> 16);
}
static __device__ __forceinline__ float bf2f(unsigned short b) {
    union { float f; unsigned u; } v; v.u = ((unsigned)b) << 16;
    return v.f;
}

// One wave (64 lanes) processes one 16x256 matrix X:
//   G = X X^T (bf16 hi/lo split MFMA, fp32 accum)
//   solve (G+lam I) M = (rho-1)G - lam I   (wave-synchronous Gauss-Jordan in LDS)
//   S = M*M (MFMA, M symmetric)
// Outputs per lane (C/D layout): entry (row=(lane>>4)*4+q, col=lane&15) of G and S.
__device__ __forceinline__ void solve_wave(const float* __restrict__ Xp,
                                           float lam, float rho,
                                           float (*Aug)[34], int lane,
                                           f32x4* g_out, f32x4* s_out) {
    const int arow = lane & 15;   // A/B fragment row (and col)
    const int kgrp = lane >> 4;   // 0..3

    // ---- load X fragments: 8 chunks x 8 contiguous floats per lane ----
    float x[64];
    const float* base = Xp + arow * Dq + kgrp * 8;
#pragma unroll
    for (int c = 0; c < 8; ++c) {
        const float4 a = *reinterpret_cast<const float4*>(base + c * 32);
        const float4 b = *reinterpret_cast<const float4*>(base + c * 32 + 4);
        x[c * 8 + 0] = a.x; x[c * 8 + 1] = a.y; x[c * 8 + 2] = a.z; x[c * 8 + 3] = a.w;
        x[c * 8 + 4] = b.x; x[c * 8 + 5] = b.y; x[c * 8 + 6] = b.z; x[c * 8 + 7] = b.w;
    }

    // ---- Gram via MFMA with hi/lo bf16 split ----
    f32x4 g = {0.f, 0.f, 0.f, 0.f};
#pragma unroll
    for (int c = 0; c < 8; ++c) {
        s16x8 h, lo;
#pragma unroll
        for (int e = 0; e < 8; ++e) {
            const float xv = x[c * 8 + e];
            const unsigned short hb = f2bf(xv);
            h[e]  = (short)hb;
            lo[e] = (short)f2bf(xv - bf2f(hb));
        }
        g = __builtin_amdgcn_mfma_f32_16x16x32_bf16(h, h, g, 0, 0, 0);
        g = __builtin_amdgcn_mfma_f32_16x16x32_bf16(h, lo, g, 0, 0, 0);
        g = __builtin_amdgcn_mfma_f32_16x16x32_bf16(lo, h, g, 0, 0, 0);
    }

    // ---- build augmented system in LDS (interleaved: [r][2c]=A, [r][2c+1]=RHS) ----
    const int ccol = lane & 15;
#pragma unroll
    for (int q = 0; q < 4; ++q) {
        const int rr = kgrp * 4 + q;
        const float gg = g[q];
        const float dv = (rr == ccol) ? lam : 0.f;
        float2 pr; pr.x = gg + dv; pr.y = (rho - 1.f) * gg - dv;
        *reinterpret_cast<float2*>(&Aug[rr][2 * ccol]) = pr;
    }
    __builtin_amdgcn_wave_barrier();

    // ---- wave-synchronous Gauss-Jordan (no barriers; same-wave LDS is in-order) ----
    for (int k = 0; k < Kq; ++k) {
        const float2 pv = *reinterpret_cast<const float2*>(&Aug[k][2 * k]);
        const float pinv = 1.0f / pv.x;
        const float2 pk = *reinterpret_cast<const float2*>(&Aug[k][2 * ccol]);
        float fac[4];
#pragma unroll
        for (int q = 0; q < 4; ++q) fac[q] = Aug[kgrp * 4 + q][2 * k];
        __builtin_amdgcn_wave_barrier();
#pragma unroll
        for (int q = 0; q < 4; ++q) {
            const int rr = kgrp * 4 + q;
            float2 cur = *reinterpret_cast<const float2*>(&Aug[rr][2 * ccol]);
            const float f = fac[q] * pinv;
            float2 nw;
            nw.x = (rr == k) ? pk.x * pinv : cur.x - f * pk.x;
            nw.y = (rr == k) ? pk.y * pinv : cur.y - f * pk.y;
            *reinterpret_cast<float2*>(&Aug[rr][2 * ccol]) = nw;
        }
        __builtin_amdgcn_wave_barrier();
    }

    // ---- S = M*M via MFMA (M symmetric; K=16 zero-padded to 32) ----
    s16x8 mh, ml;
#pragma unroll
    for (int e = 0; e < 8; ++e) {
        const int kk = (kgrp & 1) * 8 + e;          // 0..15, valid for all lanes
        const float mv = (lane < 32) ? Aug[arow][2 * kk + 1] : 0.f;
        const unsigned short hb = f2bf(mv);
        mh[e] = (short)hb;
        ml[e] = (short)f2bf(mv - bf2f(hb));
    }
    f32x4 s = {0.f, 0.f, 0.f, 0.f};
    s = __builtin_amdgcn_mfma_f32_16x16x32_bf16(mh, mh, s, 0, 0, 0);
    s = __builtin_amdgcn_mfma_f32_16x16x32_bf16(mh, ml, s, 0, 0, 0);
    s = __builtin_amdgcn_mfma_f32_16x16x32_bf16(ml, mh, s, 0, 0, 0);

    *g_out = g;
    *s_out = s;
}

__global__ __launch_bounds__(256) void phase1_kernel(const float* __restrict__ img,
                                                     const float* __restrict__ r,
                                                     float* __restrict__ ws) {
    __shared__ __align__(16) float Aug[4][Kq][34];
    const int tid = threadIdx.x;
    const int w = tid >> 6, lane = tid & 63;
    const float lam = (float(Bq) / float(Dq)) * expf(r[0]) + 1e-6f;
    const float rho = expf(r[1]);
    f32x4 g, s;
    solve_wave(img + w * (Kq * Dq), lam, rho, Aug[w], lane, &g, &s);
    reinterpret_cast<f32x4*>(ws)[w * 64 + lane] = s;          // S1[b]
    reinterpret_cast<f32x4*>(ws + 1024)[w * 64 + lane] = g;   // G_I[b]
}

__global__ __launch_bounds__(64) void phase2_kernel(const float* __restrict__ text,
                                                    const float* __restrict__ r,
                                                    const float* __restrict__ alp,
                                                    const float* __restrict__ scale,
                                                    const float* __restrict__ sg,
                                                    float* __restrict__ logits) {
    __shared__ __align__(16) float Aug[Kq][34];
    const int n = blockIdx.x;
    const int lane = threadIdx.x;
    const float lam = (float(Nq) / float(Dq)) * expf(r[2]) + 1e-6f;
    const float rho = expf(r[3]);
    f32x4 g, s;
    solve_wave(text + n * (Kq * Dq), lam, rho, Aug, lane, &g, &s);

    float p[8];
#pragma unroll
    for (int b = 0; b < 4; ++b) {
        const f32x4 s1 = reinterpret_cast<const f32x4*>(sg)[b * 64 + lane];
        const f32x4 gi = reinterpret_cast<const f32x4*>(sg + 1024)[b * 64 + lane];
        p[b]     = s1.x * g.x + s1.y * g.y + s1.z * g.z + s1.w * g.w;  // <S1[b], G_T>
        p[4 + b] = gi.x * s.x + gi.y * s.y + gi.z * s.z + gi.w * s.w;  // <S2, G_I[b]>
    }
#pragma unroll
    for (int off = 32; off; off >>= 1) {
#pragma unroll
        for (int q = 0; q < 8; ++q) p[q] += __shfl_down(p[q], off, 64);
    }
    if (lane == 0) {
        const float a = alp[0], sc = scale[0];
#pragma unroll
        for (int b = 0; b < 4; ++b) {
            const float d1 = -p[b] * (1.f / Kq);
            const float d2 = -p[4 + b] * (1.f / Kq);
            logits[b * Nq + n] = sc * (a * d1 + (1.f - a) * d2);
        }
    }
}

__global__ __launch_bounds__(256) void phase3_kernel(const float* __restrict__ logits,
                                                     const float* __restrict__ lsc,
                                                     float* __restrict__ out) {
    const int b   = blockIdx.x;
    const int tid = threadIdx.x;
    const float* row = logits + b * Nq;
    __shared__ float sh[4];
    float v[8];
    float mx = -INFINITY;
#pragma unroll
    for (int q = 0; q < 8; ++q) {
        v[q] = row[tid + q * 256];
        mx = fmaxf(mx, v[q]);
    }
#pragma unroll
    for (int off = 32; off; off >>= 1) mx = fmaxf(mx, __shfl_down(mx, off, 64));
    if ((tid & 63) == 0) sh[tid >> 6] = mx;
    __syncthreads();
    mx = fmaxf(fmaxf(sh[0], sh[1]), fmaxf(sh[2], sh[3]));

    float sum = 0.f;
#pragma unroll
    for (int q = 0; q < 8; ++q) sum += expf(v[q] - mx);
#pragma unroll
    for (int off = 32; off; off >>= 1) sum += __shfl_down(sum, off, 64);
    __syncthreads();
    if ((tid & 63) == 0) sh[tid >> 6] = sum;
    __syncthreads();
    sum = sh[0] + sh[1] + sh[2] + sh[3];

    const float lse = mx + logf(sum);
#pragma unroll
    for (int q = 0; q < 8; ++q) out[b * Nq + tid + q * 256] = v[q] - lse;
    if (b == 0 && tid == 0) out[Bq * Nq] = 1.f / (1.f + expf(-lsc[0]));
}

extern "C" void kernel_launch(void* const* d_in, const int* in_sizes, int n_in,
                              void* d_out, int out_size, void* d_ws, size_t ws_size,
                              hipStream_t stream) {
    const float* img   = (const float*)d_in[0];
    const float* text  = (const float*)d_in[1];
    const float* r     = (const float*)d_in[2];
    const float* alp   = (const float*)d_in[3];
    const float* scale = (const float*)d_in[4];
    const float* lsc   = (const float*)d_in[5];
    float* ws  = (float*)d_ws;
    float* out = (float*)d_out;

    phase1_kernel<<<1, 256, 0, stream>>>(img, r, ws);
    phase2_kernel<<<Nq, 64, 0, stream>>>(text, r, alp, scale, ws, ws + 2048);
    phase3_kernel<<<Bq, 256, 0, stream>>>(ws + 2048, lsc, out);
}

// Round 3
// 24.979 us; speedup vs baseline: 1.5671x; 1.0020x over previous
//
#include <hip/hip_runtime.h>
#include <math.h>

#define Bq 4
#define Kq 16
#define Nq 2048
#define Dq 256

typedef float f32x4 __attribute__((ext_vector_type(4)));
typedef short s16x8 __attribute__((ext_vector_type(8)));
typedef unsigned int u32;

union frag_u { s16x8 v; u32 w[4]; };

static __device__ __forceinline__ u32 cvtpk(float a, float b) {
    u32 r;
    asm("v_cvt_pk_bf16_f32 %0, %1, %2" : "=v"(r) : "v"(a), "v"(b));
    return r;
}

// 2 floats -> packed hi-bf16 word + packed lo-bf16 word (hi/lo split)
static __device__ __forceinline__ void cvt2(float a, float b, u32* hw, u32* lw) {
    const u32 h = cvtpk(a, b);
    const float h0 = __uint_as_float(h << 16);
    const float h1 = __uint_as_float(h & 0xFFFF0000u);
    *hw = h;
    *lw = cvtpk(a - h0, b - h1);
}

static __device__ __forceinline__ void conv8(const float4 a, const float4 b,
                                             s16x8* hi, s16x8* lo) {
    frag_u H, L;
    cvt2(a.x, a.y, &H.w[0], &L.w[0]);
    cvt2(a.z, a.w, &H.w[1], &L.w[1]);
    cvt2(b.x, b.y, &H.w[2], &L.w[2]);
    cvt2(b.z, b.w, &H.w[3], &L.w[3]);
    *hi = H.v; *lo = L.v;
}

#define MFMA(A, B, C) __builtin_amdgcn_mfma_f32_16x16x32_bf16((A), (B), (C), 0, 0, 0)

// One fused kernel: 512 blocks x 256 threads. Wave w of each block solves
// img matrix w (redundant across blocks; img is L2-resident) and text matrix
// n = 4*blk + w. S1/G_I exchanged block-locally via LDS; logits written out.
__global__ __launch_bounds__(256) void fused_kernel(const float* __restrict__ img,
                                                    const float* __restrict__ text,
                                                    const float* __restrict__ r,
                                                    const float* __restrict__ alp,
                                                    const float* __restrict__ scale,
                                                    float* __restrict__ logits) {
    __shared__ __align__(16) float AugI[4][Kq][34];
    __shared__ __align__(16) float AugT[4][Kq][34];
    __shared__ __align__(16) f32x4 shS1[4][64];
    __shared__ __align__(16) f32x4 shGI[4][64];

    const int tid  = threadIdx.x;
    const int w    = tid >> 6, lane = tid & 63;
    const int arow = lane & 15, kgrp = lane >> 4, ccol = arow;
    const int n    = blockIdx.x * 4 + w;

    const float lamI = (float(Bq) / float(Dq)) * expf(r[0]) + 1e-6f;
    const float rhoI = expf(r[1]);
    const float lamT = (float(Nq) / float(Dq)) * expf(r[2]) + 1e-6f;
    const float rhoT = expf(r[3]);

    // ---- load both matrices' fragments (img from L2, text from HBM) ----
    const float* baseI = img  + w * (Kq * Dq) + arow * Dq + kgrp * 8;
    const float* baseT = text + n * (Kq * Dq) + arow * Dq + kgrp * 8;
    float4 xi[16], xt[16];
#pragma unroll
    for (int c = 0; c < 8; ++c) {
        xi[2 * c]     = *reinterpret_cast<const float4*>(baseI + c * 32);
        xi[2 * c + 1] = *reinterpret_cast<const float4*>(baseI + c * 32 + 4);
        xt[2 * c]     = *reinterpret_cast<const float4*>(baseT + c * 32);
        xt[2 * c + 1] = *reinterpret_cast<const float4*>(baseT + c * 32 + 4);
    }

    // ---- Grams via MFMA (hi/lo bf16 split) ----
    f32x4 gI = {0.f, 0.f, 0.f, 0.f}, gT = {0.f, 0.f, 0.f, 0.f};
#pragma unroll
    for (int c = 0; c < 8; ++c) {
        s16x8 hi, lo;
        conv8(xi[2 * c], xi[2 * c + 1], &hi, &lo);
        gI = MFMA(hi, hi, gI); gI = MFMA(hi, lo, gI); gI = MFMA(lo, hi, gI);
        conv8(xt[2 * c], xt[2 * c + 1], &hi, &lo);
        gT = MFMA(hi, hi, gT); gT = MFMA(hi, lo, gT); gT = MFMA(lo, hi, gT);
    }

    // ---- build augmented systems (interleaved A|RHS) ----
    float (*AI)[34] = AugI[w];
    float (*AT)[34] = AugT[w];
#pragma unroll
    for (int q = 0; q < 4; ++q) {
        const int rr = kgrp * 4 + q;
        const float dI = (rr == ccol) ? lamI : 0.f;
        const float dT = (rr == ccol) ? lamT : 0.f;
        float2 pI; pI.x = gI[q] + dI; pI.y = (rhoI - 1.f) * gI[q] - dI;
        float2 pT; pT.x = gT[q] + dT; pT.y = (rhoT - 1.f) * gT[q] - dT;
        *reinterpret_cast<float2*>(&AI[rr][2 * ccol]) = pI;
        *reinterpret_cast<float2*>(&AT[rr][2 * ccol]) = pT;
    }
    __builtin_amdgcn_wave_barrier();

    // ---- dual wave-synchronous Gauss-Jordan (independent chains interleave) ----
    for (int k = 0; k < Kq; ++k) {
        const float2 pvI = *reinterpret_cast<const float2*>(&AI[k][2 * k]);
        const float2 pvT = *reinterpret_cast<const float2*>(&AT[k][2 * k]);
        const float2 pkI = *reinterpret_cast<const float2*>(&AI[k][2 * ccol]);
        const float2 pkT = *reinterpret_cast<const float2*>(&AT[k][2 * ccol]);
        const float piI = 1.f / pvI.x;
        const float piT = 1.f / pvT.x;
        float facI[4], facT[4];
#pragma unroll
        for (int q = 0; q < 4; ++q) {
            facI[q] = AI[kgrp * 4 + q][2 * k];
            facT[q] = AT[kgrp * 4 + q][2 * k];
        }
        __builtin_amdgcn_wave_barrier();
#pragma unroll
        for (int q = 0; q < 4; ++q) {
            const int rr = kgrp * 4 + q;
            float2 cI = *reinterpret_cast<const float2*>(&AI[rr][2 * ccol]);
            float2 cT = *reinterpret_cast<const float2*>(&AT[rr][2 * ccol]);
            const float fI = facI[q] * piI;
            const float fT = facT[q] * piT;
            float2 nI, nT;
            nI.x = (rr == k) ? pkI.x * piI : cI.x - fI * pkI.x;
            nI.y = (rr == k) ? pkI.y * piI : cI.y - fI * pkI.y;
            nT.x = (rr == k) ? pkT.x * piT : cT.x - fT * pkT.x;
            nT.y = (rr == k) ? pkT.y * piT : cT.y - fT * pkT.y;
            *reinterpret_cast<float2*>(&AI[rr][2 * ccol]) = nI;
            *reinterpret_cast<float2*>(&AT[rr][2 * ccol]) = nT;
        }
        __builtin_amdgcn_wave_barrier();
    }

    // ---- S = M*M via MFMA (M symmetric, K=16 zero-padded to 32) ----
    frag_u HImg, LImg, HTxt, LTxt;
#pragma unroll
    for (int e = 0; e < 8; e += 2) {
        const int kk = (kgrp & 1) * 8 + e;
        const bool vld = (lane < 32);
        const float i0 = vld ? AI[arow][2 * kk + 1]       : 0.f;
        const float i1 = vld ? AI[arow][2 * (kk + 1) + 1] : 0.f;
        const float t0 = vld ? AT[arow][2 * kk + 1]       : 0.f;
        const float t1 = vld ? AT[arow][2 * (kk + 1) + 1] : 0.f;
        cvt2(i0, i1, &HImg.w[e >> 1], &LImg.w[e >> 1]);
        cvt2(t0, t1, &HTxt.w[e >> 1], &LTxt.w[e >> 1]);
    }
    f32x4 sI = {0.f, 0.f, 0.f, 0.f}, sT = {0.f, 0.f, 0.f, 0.f};
    sI = MFMA(HImg.v, HImg.v, sI); sI = MFMA(HImg.v, LImg.v, sI); sI = MFMA(LImg.v, HImg.v, sI);
    sT = MFMA(HTxt.v, HTxt.v, sT); sT = MFMA(HTxt.v, LTxt.v, sT); sT = MFMA(LTxt.v, HTxt.v, sT);

    // ---- block-local exchange of img results, then dots ----
    shS1[w][lane] = sI;
    shGI[w][lane] = gI;
    __syncthreads();

    float p[8];
#pragma unroll
    for (int b = 0; b < 4; ++b) {
        const f32x4 s1 = shS1[b][lane];
        const f32x4 gi = shGI[b][lane];
        p[b]     = s1.x * gT.x + s1.y * gT.y + s1.z * gT.z + s1.w * gT.w;  // <S1[b], G_T>
        p[4 + b] = gi.x * sT.x + gi.y * sT.y + gi.z * sT.z + gi.w * sT.w;  // <S2, G_I[b]>
    }
#pragma unroll
    for (int off = 32; off; off >>= 1) {
#pragma unroll
        for (int q = 0; q < 8; ++q) p[q] += __shfl_down(p[q], off, 64);
    }
    if (lane == 0) {
        const float a = alp[0], sc = scale[0];
#pragma unroll
        for (int b = 0; b < 4; ++b) {
            const float d1 = -p[b] * (1.f / Kq);
            const float d2 = -p[4 + b] * (1.f / Kq);
            logits[b * Nq + n] = sc * (a * d1 + (1.f - a) * d2);
        }
    }
}

__global__ __launch_bounds__(256) void softmax_kernel(const float* __restrict__ logits,
                                                      const float* __restrict__ lsc,
                                                      float* __restrict__ out) {
    const int b   = blockIdx.x;
    const int tid = threadIdx.x;
    const float* row = logits + b * Nq;
    __shared__ float sh[4];
    float v[8];
    float mx = -INFINITY;
#pragma unroll
    for (int q = 0; q < 8; ++q) {
        v[q] = row[tid + q * 256];
        mx = fmaxf(mx, v[q]);
    }
#pragma unroll
    for (int off = 32; off; off >>= 1) mx = fmaxf(mx, __shfl_down(mx, off, 64));
    if ((tid & 63) == 0) sh[tid >> 6] = mx;
    __syncthreads();
    mx = fmaxf(fmaxf(sh[0], sh[1]), fmaxf(sh[2], sh[3]));

    float sum = 0.f;
#pragma unroll
    for (int q = 0; q < 8; ++q) sum += expf(v[q] - mx);
#pragma unroll
    for (int off = 32; off; off >>= 1) sum += __shfl_down(sum, off, 64);
    __syncthreads();
    if ((tid & 63) == 0) sh[tid >> 6] = sum;
    __syncthreads();
    sum = sh[0] + sh[1] + sh[2] + sh[3];

    const float lse = mx + logf(sum);
#pragma unroll
    for (int q = 0; q < 8; ++q) out[b * Nq + tid + q * 256] = v[q] - lse;
    if (b == 0 && tid == 0) out[Bq * Nq] = 1.f / (1.f + expf(-lsc[0]));
}

extern "C" void kernel_launch(void* const* d_in, const int* in_sizes, int n_in,
                              void* d_out, int out_size, void* d_ws, size_t ws_size,
                              hipStream_t stream) {
    const float* img   = (const float*)d_in[0];
    const float* text  = (const float*)d_in[1];
    const float* r     = (const float*)d_in[2];
    const float* alp   = (const float*)d_in[3];
    const float* scale = (const float*)d_in[4];
    const float* lsc   = (const float*)d_in[5];
    float* ws  = (float*)d_ws;   // logits: 4*2048 floats
    float* out = (float*)d_out;

    fused_kernel<<<Nq / 4, 256, 0, stream>>>(img, text, r, alp, scale, ws);
    softmax_kernel<<<Bq, 256, 0, stream>>>(ws, lsc, out);
}